// Round 1
// baseline (238.102 us; speedup 1.0000x reference)
//
#include <hip/hip_runtime.h>
#include <cstdint>
#include <cstddef>

#define EPSF 1e-5f
#define LEAKF 0.01f
#define AVGD 3.3f

static constexpr int Nn = 256, DIN = 128, DE = 64, Hn = 128;
static constexpr int BN = 2048;            // nodes
static constexpr int KP = 1664;            // post-GEMM K  = 128 input + 1536 m
static constexpr int KM = 1536;            // m-features per node

typedef short bf16x8 __attribute__((ext_vector_type(8)));
typedef float f32x4  __attribute__((ext_vector_type(4)));
union BF8 { bf16x8 v; uint16_t u[8]; };

__device__ __forceinline__ float bf2f(uint16_t u) { return __uint_as_float(((uint32_t)u) << 16); }
__device__ __forceinline__ float bflo(uint32_t u)  { return __uint_as_float(u << 16); }
__device__ __forceinline__ uint16_t f2bf(float f) {
  uint32_t u = __float_as_uint(f);
  u += 0x7fffu + ((u >> 16) & 1u);   // RNE
  return (uint16_t)(u >> 16);
}

// Per-block inline dtype probe (bf16 vs fp32 storage). Wave-uniform.
__device__ __forceinline__ int detect_bf16(const uint32_t* w) {
  float lo = bflo(w[threadIdx.x & 63]);
  unsigned long long ok = __ballot(fabsf(lo) < 64.f);
  return ok == 0xFFFFFFFFFFFFFFFFull;
}
__device__ __forceinline__ float loadf(const void* p, size_t i, int isbf) {
  return isbf ? bf2f(((const uint16_t*)p)[i]) : ((const float*)p)[i];
}
__device__ __forceinline__ bf16x8 load_a8(const void* p, size_t elem, int isbf) {
  if (isbf) return *(const bf16x8*)((const uint16_t*)p + elem);
  const float* s = (const float*)p + elem;
  BF8 r;
  #pragma unroll
  for (int e = 0; e < 8; e++) r.u[e] = f2bf(s[e]);
  return r.v;
}
__device__ __forceinline__ f32x4 mfma16(bf16x8 a, bf16x8 b, f32x4 c) {
  return __builtin_amdgcn_mfma_f32_16x16x32_bf16(a, b, c, 0, 0, 0);
}

// ================= P1: prep (blocks 0..275)  +  k1 GEMM (blocks 276..787) ===========
// prep map: 0..207 postT transpose | 208..223 mixT transpose | 224..227 WeB copy
//           228..251 Wihb | 252..275 Whhb
// k1: hi = input@Wi + pre_b ; hj = input@Wj  — reads RAW input/pre_W (no prep dep!)
__global__ __launch_bounds__(256) void k_prep1(
    const void* __restrict__ input, const void* __restrict__ pre_W,
    const void* __restrict__ pre_b, const void* __restrict__ post_W,
    const void* __restrict__ mix_W, const void* __restrict__ Wih,
    const void* __restrict__ Whh,
    uint16_t* __restrict__ postTb, uint16_t* __restrict__ mixTb,
    uint16_t* __restrict__ WeB, uint16_t* __restrict__ Wihb,
    uint16_t* __restrict__ Whhb,
    float* __restrict__ hi, float* __restrict__ hj) {
  __shared__ float tile[32][33];
  int isbf = detect_bf16((const uint32_t*)input);
  int b = blockIdx.x, tid = threadIdx.x;

  if (b >= 276) {   // ---- k1 sub-kernel: 512 blocks x 4 waves ----
    int lane = tid & 63, w = tid >> 6;
    int wg = (b - 276) * 4 + w;               // 0..2047
    int rt = wg >> 4, nt = wg & 15;
    int ishj = nt >> 3, ct = nt & 7;
    int m16 = lane & 15, quad = lane >> 4;
    int col = ct * 16 + m16;
    int row = rt * 16 + m16;
    int kbase = ishj ? 128 : 0;
    f32x4 acc = {0.f, 0.f, 0.f, 0.f};
    #pragma unroll
    for (int kt = 0; kt < 4; kt++) {
      bf16x8 a = load_a8(input, (size_t)row * 128 + kt * 32 + quad * 8, isbf);
      BF8 bb;
      #pragma unroll
      for (int j = 0; j < 8; j++)
        bb.u[j] = f2bf(loadf(pre_W, (size_t)(kbase + kt * 32 + quad * 8 + j) * 128 + col, isbf));
      acc = mfma16(a, bb.v, acc);
    }
    float bias = ishj ? 0.f : loadf(pre_b, col, isbf);
    float* dst = ishj ? hj : hi;
    #pragma unroll
    for (int r = 0; r < 4; r++)
      dst[(size_t)(rt * 16 + quad * 4 + r) * 128 + col] = acc[r] + bias;
    return;
  }

  if (b < 224) {    // ---- transposes (bf16 col-major out) ----
    const void* src; uint16_t* bdst; int R, t;
    if (b < 208) { src = post_W; bdst = postTb; R = KP;  t = b; }
    else         { src = mix_W;  bdst = mixTb;  R = 128; t = b - 208; }
    int bx = t & 3, by = t >> 2;
    int tx = tid & 31, ty = tid >> 5;          // 32 x 8
    int c0 = bx * 32, r0 = by * 32;
    #pragma unroll
    for (int dy = 0; dy < 32; dy += 8)
      tile[ty + dy][tx] = loadf(src, (size_t)(r0 + ty + dy) * 128 + (c0 + tx), isbf);
    __syncthreads();
    #pragma unroll
    for (int dy = 0; dy < 32; dy += 8)
      bdst[(size_t)(c0 + ty + dy) * R + (r0 + tx)] = f2bf(tile[tx][ty + dy]);
  } else {          // ---- plain bf16 copies ----
    const void* src; uint16_t* dst; int base; size_t soff = 0;
    if (b < 228)      { src = pre_W; dst = WeB;  base = (b - 224) * 2048; soff = 256 * 128; }
    else if (b < 252) { src = Wih;   dst = Wihb; base = (b - 228) * 2048; }
    else              { src = Whh;   dst = Whhb; base = (b - 252) * 2048; }
    int i = base + tid * 8;
    uint16_t v[8];
    if (isbf) *(uint4*)v = *(const uint4*)((const uint16_t*)src + soff + i);
    else { const float* s = (const float*)src + soff + i;
           #pragma unroll
           for (int e = 0; e < 8; e++) v[e] = f2bf(s[e]); }
    *(uint4*)(dst + i) = *(uint4*)v;
  }
}

// ================= P2: edge aggregation via MFMA -> Mb[bi, 0:1536] ==================
// 1 block per node, 256 thr (4 waves); 16-edge chunks, DOUBLE-BUFFERED af staging.
__global__ __launch_bounds__(256) void k2_mfma(
    const void* __restrict__ input, const void* __restrict__ adj_raw,
    const void* __restrict__ af_raw,
    const float* __restrict__ hi, const float* __restrict__ hj,
    const uint16_t* __restrict__ WeB, uint16_t* __restrict__ Mb) {
  __shared__ int s_cnt;
  __shared__ int nbr[Nn];
  __shared__ __align__(16) uint16_t A_lds[2][16 * 72];   // stride 72: 2-way banks (free)
  int isbf = detect_bf16((const uint32_t*)input);
  int bi = blockIdx.x, tid = threadIdx.x;
  if (tid == 0) s_cnt = 0;
  __syncthreads();
  {
    float a = loadf(adj_raw, (size_t)bi * Nn + tid, isbf);
    if (a > 0.f) nbr[atomicAdd(&s_cnt, 1)] = tid;
  }
  __syncthreads();
  int cnt = s_cnt;

  int lane = tid & 63, w = tid >> 6;
  int m16 = lane & 15, quad = lane >> 4;
  int col0 = w * 32 + m16, col1 = col0 + 16;

  // B fragments: We rows 0..63 of WeB (row-major B[k][n])
  BF8 b00, b01, b10, b11;
  #pragma unroll
  for (int j = 0; j < 8; j++) {
    int k0 = quad * 8 + j, k1 = k0 + 32;
    b00.u[j] = WeB[(size_t)k0 * 128 + col0];
    b01.u[j] = WeB[(size_t)k1 * 128 + col0];
    b10.u[j] = WeB[(size_t)k0 * 128 + col1];
    b11.u[j] = WeB[(size_t)k1 * 128 + col1];
  }
  float base0 = hi[(size_t)bi * 128 + col0];
  float base1 = hi[(size_t)bi * 128 + col1];
  const float* hjb = &hj[(size_t)(bi & ~(Nn - 1)) * 128];

  float s1a = 0.f, s2a = 0.f, mxa = -1e30f, mna = 1e30f;
  float s1b = 0.f, s2b = 0.f, mxb = -1e30f, mnb = 1e30f;

  auto stage = [&](int ce, int buf) {
    if (tid < 128) {                 // 16 edge rows x 64 De (clamped tail)
      int e = tid >> 3, seg = tid & 7;
      int ei = ce + e; if (ei >= cnt) ei = cnt - 1;
      int j = nbr[ei];
      uint16_t v[8];
      if (isbf)
        *(uint4*)v = *(const uint4*)((const uint16_t*)af_raw + ((size_t)bi * Nn + j) * DE + seg * 8);
      else {
        const float* s = (const float*)af_raw + ((size_t)bi * Nn + j) * DE + seg * 8;
        #pragma unroll
        for (int x = 0; x < 8; x++) v[x] = f2bf(s[x]);
      }
      *(uint4*)&A_lds[buf][e * 72 + seg * 8] = *(uint4*)v;
    }
  };

  if (cnt > 0) stage(0, 0);
  __syncthreads();

  for (int ce = 0; ce < cnt; ce += 16) {
    int cur = (ce >> 4) & 1;
    if (ce + 16 < cnt) stage(ce + 16, cur ^ 1);   // prefetch next chunk (other buffer)
    float hjv0[4], hjv1[4]; int vld[4];
    #pragma unroll
    for (int r = 0; r < 4; r++) {
      int e = ce + quad * 4 + r;
      vld[r] = (e < cnt);
      int j = nbr[vld[r] ? e : (cnt - 1)];
      hjv0[r] = hjb[(size_t)j * 128 + col0];
      hjv1[r] = hjb[(size_t)j * 128 + col1];
    }
    bf16x8 a0 = *(const bf16x8*)&A_lds[cur][m16 * 72 + quad * 8];
    bf16x8 a1 = *(const bf16x8*)&A_lds[cur][m16 * 72 + 32 + quad * 8];
    f32x4 C0 = {0.f,0.f,0.f,0.f}, C1 = C0;
    C0 = mfma16(a0, b00.v, C0); C0 = mfma16(a1, b01.v, C0);
    C1 = mfma16(a0, b10.v, C1); C1 = mfma16(a1, b11.v, C1);
    #pragma unroll
    for (int r = 0; r < 4; r++) {
      float h0 = base0 + hjv0[r] + C0[r];
      float h1 = base1 + hjv1[r] + C1[r];
      if (vld[r]) {
        s1a += h0; s2a += h0 * h0; mxa = fmaxf(mxa, h0); mna = fminf(mna, h0);
        s1b += h1; s2b += h1 * h1; mxb = fmaxf(mxb, h1); mnb = fminf(mnb, h1);
      }
    }
    __syncthreads();   // buf[cur] reads done; buf[cur^1] stage writes visible
  }

  // cross-quad reduce: lanes {m16, +16, +32, +48} hold partials of the same col
  #pragma unroll
  for (int off = 16; off <= 32; off <<= 1) {
    s1a += __shfl_xor(s1a, off); s2a += __shfl_xor(s2a, off);
    mxa = fmaxf(mxa, __shfl_xor(mxa, off)); mna = fminf(mna, __shfl_xor(mna, off));
    s1b += __shfl_xor(s1b, off); s2b += __shfl_xor(s2b, off);
    mxb = fmaxf(mxb, __shfl_xor(mxb, off)); mnb = fminf(mnb, __shfl_xor(mnb, off));
  }
  if (quad == 0) {
    float deg = (float)cnt, degc = fmaxf(deg, EPSF);
    float slog = logf(deg + 1.f) / AVGD;
    float inv  = 1.f / (slog + EPSF);
    uint16_t* mo = Mb + (size_t)bi * KM;
    #pragma unroll
    for (int t = 0; t < 2; t++) {
      float s1 = t ? s1b : s1a, s2 = t ? s2b : s2a;
      float mx = t ? mxb : mxa, mn = t ? mnb : mna;
      int col = t ? col1 : col0;
      float mean = s1 / degc;
      float var  = fmaxf(s2 / degc - mean * mean, 0.f);
      float stdv = sqrtf(var + EPSF);
      if (cnt == 0) { mx = 0.f; mn = 0.f; }
      mo[0*128+col]  = f2bf(mean);        mo[1*128+col]  = f2bf(mx);
      mo[2*128+col]  = f2bf(mn);          mo[3*128+col]  = f2bf(stdv);
      mo[4*128+col]  = f2bf(mean * slog); mo[5*128+col]  = f2bf(mx * slog);
      mo[6*128+col]  = f2bf(mn * slog);   mo[7*128+col]  = f2bf(stdv * slog);
      mo[8*128+col]  = f2bf(mean * inv);  mo[9*128+col]  = f2bf(mx * inv);
      mo[10*128+col] = f2bf(mn * inv);    mo[11*128+col] = f2bf(stdv * inv);
    }
  }
}

// ================= P3: post GEMM -> mix+leaky -> GRU -> out (fully fused) ===========
// 128 blocks x 8 waves; block = 16 nodes; wave w owns col-tile w. y lives in LDS only.
__global__ __launch_bounds__(512) void k3_fused(
    const void* __restrict__ input, const uint16_t* __restrict__ Mb,
    const uint16_t* __restrict__ postTb, const void* __restrict__ post_b,
    const uint16_t* __restrict__ mixTb, const void* __restrict__ mix_b,
    const uint16_t* __restrict__ Wihb, const uint16_t* __restrict__ Whhb,
    const void* __restrict__ hidden, void* __restrict__ out) {
  constexpr int SX = 136;
  __shared__ __align__(16) uint16_t y_s[16 * SX];
  __shared__ __align__(16) uint16_t x_s[16 * SX];
  __shared__ __align__(16) uint16_t hid_s[16 * SX];
  int isbf = detect_bf16((const uint32_t*)input);
  int tid = threadIdx.x;
  int n0 = blockIdx.x * 16;
  if (tid < 256) {   // stage hidden (16 x 128 bf16) straight from raw
    int row = tid >> 4, c = (tid & 15) * 8;
    uint16_t v[8];
    if (isbf) *(uint4*)v = *(const uint4*)((const uint16_t*)hidden + (size_t)(n0 + row) * 128 + c);
    else { const float* s = (const float*)hidden + (size_t)(n0 + row) * 128 + c;
           #pragma unroll
           for (int e = 0; e < 8; e++) v[e] = f2bf(s[e]); }
    *(uint4*)&hid_s[row * SX + c] = *(uint4*)v;
  }
  int lane = tid & 63, w = tid >> 6;
  int m16 = lane & 15, quad = lane >> 4;
  int col = w * 16 + m16;

  // ---- post GEMM: y[16 x 16 tile], K = 128 (raw input) + 1536 (Mb), dual chains ----
  f32x4 acc0 = {0.f,0.f,0.f,0.f}, acc1 = acc0;
  const uint16_t* bp = postTb + (size_t)col * KP + quad * 8;
  #pragma unroll
  for (int kt = 0; kt < 4; kt += 2) {
    bf16x8 a0 = load_a8(input, (size_t)(n0 + m16) * 128 + kt * 32 + quad * 8, isbf);
    bf16x8 a1 = load_a8(input, (size_t)(n0 + m16) * 128 + kt * 32 + 32 + quad * 8, isbf);
    acc0 = mfma16(a0, *(const bf16x8*)(bp + kt * 32), acc0);
    acc1 = mfma16(a1, *(const bf16x8*)(bp + kt * 32 + 32), acc1);
  }
  const uint16_t* mp  = Mb + (size_t)(n0 + m16) * KM + quad * 8;
  const uint16_t* bp2 = bp + 4 * 32;
  #pragma unroll 4
  for (int kt = 0; kt < 48; kt += 2) {
    bf16x8 a0 = *(const bf16x8*)(mp + kt * 32);
    bf16x8 a1 = *(const bf16x8*)(mp + kt * 32 + 32);
    acc0 = mfma16(a0, *(const bf16x8*)(bp2 + kt * 32), acc0);
    acc1 = mfma16(a1, *(const bf16x8*)(bp2 + kt * 32 + 32), acc1);
  }
  float pb = loadf(post_b, col, isbf);
  #pragma unroll
  for (int r = 0; r < 4; r++)
    y_s[(quad * 4 + r) * SX + col] = f2bf(acc0[r] + acc1[r] + pb);
  __syncthreads();   // y_s ready (also covers hid_s staging)

  // ---- mix + leaky ----
  f32x4 acc = {0.f,0.f,0.f,0.f};
  const uint16_t* ya = &y_s[m16 * SX + quad * 8];
  const uint16_t* mb = mixTb + (size_t)col * 128 + quad * 8;
  #pragma unroll
  for (int kt = 0; kt < 4; kt++)
    acc = mfma16(*(const bf16x8*)(ya + kt * 32), *(const bf16x8*)(mb + kt * 32), acc);
  float mbias = loadf(mix_b, col, isbf);
  #pragma unroll
  for (int r = 0; r < 4; r++) {
    float v = acc[r] + mbias; v = v > 0.f ? v : LEAKF * v;
    x_s[(quad * 4 + r) * SX + col] = f2bf(v);
  }
  __syncthreads();   // x_s ready

  // ---- GRU ----
  f32x4 gi[3], gh[3];
  #pragma unroll
  for (int q = 0; q < 3; q++) { gi[q] = {0.f,0.f,0.f,0.f}; gh[q] = {0.f,0.f,0.f,0.f}; }
  const uint16_t* xa = &x_s[m16 * SX + quad * 8];
  const uint16_t* ha = &hid_s[m16 * SX + quad * 8];
  #pragma unroll
  for (int kt = 0; kt < 4; kt++) {
    bf16x8 ax = *(const bf16x8*)(xa + kt * 32);
    bf16x8 ah = *(const bf16x8*)(ha + kt * 32);
    #pragma unroll
    for (int q = 0; q < 3; q++) {
      bf16x8 bi_ = *(const bf16x8*)&Wihb[(size_t)(q * 128 + col) * 128 + kt * 32 + quad * 8];
      bf16x8 bh_ = *(const bf16x8*)&Whhb[(size_t)(q * 128 + col) * 128 + kt * 32 + quad * 8];
      gi[q] = mfma16(ax, bi_, gi[q]);
      gh[q] = mfma16(ah, bh_, gh[q]);
    }
  }
  #pragma unroll
  for (int r = 0; r < 4; r++) {
    int row = quad * 4 + r;
    float rg = 1.f / (1.f + expf(-(gi[0][r] + gh[0][r])));
    float zg = 1.f / (1.f + expf(-(gi[1][r] + gh[1][r])));
    float ng = tanhf(gi[2][r] + rg * gh[2][r]);
    float hv = bf2f(hid_s[row * SX + col]);
    float res = (1.f - zg) * ng + zg * hv;
    size_t oi = (size_t)(n0 + row) * 128 + col;
    if (isbf) ((uint16_t*)out)[oi] = f2bf(res);
    else      ((float*)out)[oi]    = res;
  }
}

extern "C" void kernel_launch(void* const* d_in, const int* in_sizes, int n_in,
                              void* d_out, int out_size, void* d_ws, size_t ws_size,
                              hipStream_t stream) {
  const void* input  = d_in[0];
  const void* adj    = d_in[1];
  const void* af     = d_in[2];
  const void* hidden = d_in[3];
  const void* pre_W  = d_in[4];
  const void* pre_b  = d_in[5];
  const void* post_W = d_in[6];
  const void* post_b = d_in[7];
  const void* mix_W  = d_in[8];
  const void* mix_b  = d_in[9];
  const void* Wih    = d_in[10];
  const void* Whh    = d_in[11];

  float* ws = (float*)d_ws;
  float* hi = ws;                               // 262144 f
  float* hj = hi + 262144;                      // 262144 f
  uint16_t* postTb = (uint16_t*)(hj + 262144);  // 1664*128 = 212992
  uint16_t* mixTb  = postTb + 212992;           // 16384
  uint16_t* WeB    = mixTb + 16384;             // 64*128 = 8192
  uint16_t* Wihb   = WeB + 8192;                // 49152
  uint16_t* Whhb   = Wihb + 49152;              // 49152
  uint16_t* Mb     = Whhb + 49152;              // 2048*1536 = 3145728

  k_prep1<<<788, 256, 0, stream>>>(input, pre_W, pre_b, post_W, mix_W, Wih, Whh,
                                   postTb, mixTb, WeB, Wihb, Whhb, hi, hj);
  k2_mfma<<<BN, 256, 0, stream>>>(input, adj, af, hi, hj, WeB, Mb);
  k3_fused<<<128, 512, 0, stream>>>(input, Mb, postTb, post_b, mixTb, mix_b,
                                    Wihb, Whhb, hidden, d_out);
}

// Round 2
// 227.501 us; speedup vs baseline: 1.0466x; 1.0466x over previous
//
#include <hip/hip_runtime.h>
#include <cstdint>
#include <cstddef>

#define EPSF 1e-5f
#define LEAKF 0.01f
#define AVGD 3.3f

static constexpr int Nn = 256, DIN = 128, DE = 64, Hn = 128;
static constexpr int BN = 2048;            // nodes
static constexpr int KP = 1664;            // post-GEMM K  = 128 input + 1536 m
static constexpr int KM = 1536;            // m-features per node

typedef short bf16x8 __attribute__((ext_vector_type(8)));
typedef float f32x4  __attribute__((ext_vector_type(4)));
union BF8 { bf16x8 v; uint16_t u[8]; };

__device__ __forceinline__ float bf2f(uint16_t u) { return __uint_as_float(((uint32_t)u) << 16); }
__device__ __forceinline__ float bflo(uint32_t u)  { return __uint_as_float(u << 16); }
__device__ __forceinline__ uint16_t f2bf(float f) {
  uint32_t u = __float_as_uint(f);
  u += 0x7fffu + ((u >> 16) & 1u);   // RNE
  return (uint16_t)(u >> 16);
}

// Per-block inline dtype probe (bf16 vs fp32 storage). Wave-uniform.
__device__ __forceinline__ int detect_bf16(const uint32_t* w) {
  float lo = bflo(w[threadIdx.x & 63]);
  unsigned long long ok = __ballot(fabsf(lo) < 64.f);
  return ok == 0xFFFFFFFFFFFFFFFFull;
}
__device__ __forceinline__ float loadf(const void* p, size_t i, int isbf) {
  return isbf ? bf2f(((const uint16_t*)p)[i]) : ((const float*)p)[i];
}
__device__ __forceinline__ bf16x8 load_a8(const void* p, size_t elem, int isbf) {
  if (isbf) return *(const bf16x8*)((const uint16_t*)p + elem);
  const float* s = (const float*)p + elem;
  BF8 r;
  #pragma unroll
  for (int e = 0; e < 8; e++) r.u[e] = f2bf(s[e]);
  return r.v;
}
__device__ __forceinline__ f32x4 mfma16(bf16x8 a, bf16x8 b, f32x4 c) {
  return __builtin_amdgcn_mfma_f32_16x16x32_bf16(a, b, c, 0, 0, 0);
}

// ================= P1: prep (blocks 0..275)  +  k1 GEMM (blocks 276..787) ===========
// prep map: 0..207 postT transpose | 208..223 mixT transpose | 224..227 WeB copy
//           228..251 Wihb | 252..275 Whhb
// k1: hi = input@Wi + pre_b ; hj = input@Wj  — reads RAW input/pre_W
__global__ __launch_bounds__(256) void k_prep1(
    const void* __restrict__ input, const void* __restrict__ pre_W,
    const void* __restrict__ pre_b, const void* __restrict__ post_W,
    const void* __restrict__ mix_W, const void* __restrict__ Wih,
    const void* __restrict__ Whh,
    uint16_t* __restrict__ postTb, uint16_t* __restrict__ mixTb,
    uint16_t* __restrict__ WeB, uint16_t* __restrict__ Wihb,
    uint16_t* __restrict__ Whhb,
    float* __restrict__ hi, float* __restrict__ hj) {
  __shared__ float tile[32][33];
  int isbf = detect_bf16((const uint32_t*)input);
  int b = blockIdx.x, tid = threadIdx.x;

  if (b >= 276) {   // ---- k1 sub-kernel: 512 blocks x 4 waves ----
    int lane = tid & 63, w = tid >> 6;
    int wg = (b - 276) * 4 + w;               // 0..2047
    int rt = wg >> 4, nt = wg & 15;
    int ishj = nt >> 3, ct = nt & 7;
    int m16 = lane & 15, quad = lane >> 4;
    int col = ct * 16 + m16;
    int row = rt * 16 + m16;
    int kbase = ishj ? 128 : 0;
    f32x4 acc = {0.f, 0.f, 0.f, 0.f};
    #pragma unroll
    for (int kt = 0; kt < 4; kt++) {
      bf16x8 a = load_a8(input, (size_t)row * 128 + kt * 32 + quad * 8, isbf);
      BF8 bb;
      #pragma unroll
      for (int j = 0; j < 8; j++)
        bb.u[j] = f2bf(loadf(pre_W, (size_t)(kbase + kt * 32 + quad * 8 + j) * 128 + col, isbf));
      acc = mfma16(a, bb.v, acc);
    }
    float bias = ishj ? 0.f : loadf(pre_b, col, isbf);
    float* dst = ishj ? hj : hi;
    #pragma unroll
    for (int r = 0; r < 4; r++)
      dst[(size_t)(rt * 16 + quad * 4 + r) * 128 + col] = acc[r] + bias;
    return;
  }

  if (b < 224) {    // ---- transposes (bf16 col-major out) ----
    const void* src; uint16_t* bdst; int R, t;
    if (b < 208) { src = post_W; bdst = postTb; R = KP;  t = b; }
    else         { src = mix_W;  bdst = mixTb;  R = 128; t = b - 208; }
    int bx = t & 3, by = t >> 2;
    int tx = tid & 31, ty = tid >> 5;          // 32 x 8
    int c0 = bx * 32, r0 = by * 32;
    #pragma unroll
    for (int dy = 0; dy < 32; dy += 8)
      tile[ty + dy][tx] = loadf(src, (size_t)(r0 + ty + dy) * 128 + (c0 + tx), isbf);
    __syncthreads();
    #pragma unroll
    for (int dy = 0; dy < 32; dy += 8)
      bdst[(size_t)(c0 + ty + dy) * R + (r0 + tx)] = f2bf(tile[tx][ty + dy]);
  } else {          // ---- plain bf16 copies ----
    const void* src; uint16_t* dst; int base; size_t soff = 0;
    if (b < 228)      { src = pre_W; dst = WeB;  base = (b - 224) * 2048; soff = 256 * 128; }
    else if (b < 252) { src = Wih;   dst = Wihb; base = (b - 228) * 2048; }
    else              { src = Whh;   dst = Whhb; base = (b - 252) * 2048; }
    int i = base + tid * 8;
    uint16_t v[8];
    if (isbf) *(uint4*)v = *(const uint4*)((const uint16_t*)src + soff + i);
    else { const float* s = (const float*)src + soff + i;
           #pragma unroll
           for (int e = 0; e < 8; e++) v[e] = f2bf(s[e]); }
    *(uint4*)(dst + i) = *(uint4*)v;
  }
}

// ================= P2: per-8-node fused edge-agg + post + mix + GRU =================
// 256 blocks x 512 thr (8 waves). Wave w aggregates node n0+w (wave-private LDS dbuf,
// ZERO barriers in the edge loop), m stays in LDS (XOR-swizzled), then the block runs
// postGEMM->mix->GRU on its 8 nodes. No Mb round-trip, no separate k3 launch.
__global__ __launch_bounds__(512) void k23_fused(
    const void* __restrict__ input, const void* __restrict__ adj_raw,
    const void* __restrict__ af_raw, const float* __restrict__ hi,
    const float* __restrict__ hj, const uint16_t* __restrict__ WeB,
    const uint16_t* __restrict__ postTb, const void* __restrict__ post_b,
    const uint16_t* __restrict__ mixTb, const void* __restrict__ mix_b,
    const uint16_t* __restrict__ Wihb, const uint16_t* __restrict__ Whhb,
    const void* __restrict__ hidden, void* __restrict__ out) {
  constexpr int SX = 136;
  __shared__ __align__(16) uint16_t m_s[16 * KM];          // rows XOR-swizzled: off ^= (row&7)<<4
  __shared__ __align__(16) uint16_t A_lds[8][2][16 * 72];  // per-wave af dbuf
  __shared__ uint16_t nbr_s[8][Nn];
  __shared__ __align__(16) uint16_t y_s[16 * SX];
  __shared__ __align__(16) uint16_t x_s[16 * SX];
  __shared__ __align__(16) uint16_t hid_s[16 * SX];

  int isbf = detect_bf16((const uint32_t*)input);
  int tid = threadIdx.x;
  int n0 = blockIdx.x * 8;

  {  // zero m_s rows 8..15 (bytes 24576..49152) — read by unstored MFMA rows
    uint4 z = {0, 0, 0, 0};
    #pragma unroll
    for (int i = 0; i < 3; i++)
      *(uint4*)((char*)m_s + 24576 + (tid * 3 + i) * 16) = z;
  }
  if (tid < 256) {   // stage hidden (16 rows bf16; rows 8..15 clamped, unused)
    int row = tid >> 4, c = (tid & 15) * 8;
    int sr = n0 + row; if (sr > BN - 1) sr = BN - 1;
    uint16_t v[8];
    if (isbf) *(uint4*)v = *(const uint4*)((const uint16_t*)hidden + (size_t)sr * 128 + c);
    else { const float* s = (const float*)hidden + (size_t)sr * 128 + c;
           #pragma unroll
           for (int e = 0; e < 8; e++) v[e] = f2bf(s[e]); }
    *(uint4*)&hid_s[row * SX + c] = *(uint4*)v;
  }

  int lane = tid & 63, w = tid >> 6;
  int m16 = lane & 15, quad = lane >> 4;

  // ---------------- aggregation: wave w owns node n0 + w ----------------
  {
    int gnode = n0 + w;                       // 0..2047
    int g = gnode >> 8, nl = gnode & 255;
    // ballot-compact neighbor list (sorted) — no atomics, no barriers
    int cnt = 0;
    #pragma unroll
    for (int g4 = 0; g4 < 4; g4++) {
      float a = loadf(adj_raw, (size_t)gnode * Nn + g4 * 64 + lane, isbf);
      unsigned long long mb = __ballot(a > 0.f);
      unsigned long long below = lane ? (~0ull >> (64 - lane)) : 0ull;
      int pos = cnt + __popcll(mb & below);
      if (a > 0.f) nbr_s[w][pos] = (uint16_t)(g4 * 64 + lane);
      cnt += __popcll(mb);
    }

    // hi row + We B-fragments (registers, reused over all chunks)
    float hiv[8];
    BF8 b0[8], b1[8];
    #pragma unroll
    for (int ct = 0; ct < 8; ct++) {
      int col = ct * 16 + m16;
      hiv[ct] = hi[(size_t)gnode * 128 + col];
      #pragma unroll
      for (int j = 0; j < 8; j++) {
        b0[ct].u[j] = WeB[(size_t)(quad * 8 + j) * 128 + col];
        b1[ct].u[j] = WeB[(size_t)(32 + quad * 8 + j) * 128 + col];
      }
    }
    float s1[8], s2[8], mxv[8], mnv[8];
    #pragma unroll
    for (int ct = 0; ct < 8; ct++) { s1[ct] = 0.f; s2[ct] = 0.f; mxv[ct] = -1e30f; mnv[ct] = 1e30f; }

    int e_ = lane >> 2, seg = lane & 3;       // lane stages 16 bf16 of edge e_
    uint32_t cr[8], nr[8];
    auto load_chunk = [&](int ce, uint32_t* d) {
      int ei = ce + e_; if (ei >= cnt) ei = cnt - 1;
      int j = nbr_s[w][ei];
      size_t base = (((size_t)g * Nn + nl) * Nn + j) * DE + seg * 16;
      if (isbf) {
        *(uint4*)d       = *(const uint4*)((const uint16_t*)af_raw + base);
        *(uint4*)(d + 4) = *(const uint4*)((const uint16_t*)af_raw + base + 8);
      } else {
        const float* s = (const float*)af_raw + base;
        #pragma unroll
        for (int x = 0; x < 8; x++)
          d[x] = (uint32_t)f2bf(s[2 * x]) | ((uint32_t)f2bf(s[2 * x + 1]) << 16);
      }
    };

    if (cnt > 0) load_chunk(0, cr);
    for (int ce = 0; ce < cnt; ce += 16) {
      int bf = (ce >> 4) & 1;
      {  // cur chunk -> LDS (wave-private; dbuf removes the WAR distance-1 hazard)
        uint16_t* dst = &A_lds[w][bf][e_ * 72 + seg * 16];
        *(uint4*)dst = *(uint4*)cr;
        *(uint4*)(dst + 8) = *(uint4*)(cr + 4);
      }
      if (ce + 16 < cnt) load_chunk(ce + 16, nr);   // prefetch next (hides HBM latency)
      int vld[4], jn[4];
      #pragma unroll
      for (int r = 0; r < 4; r++) {
        int e = ce + quad * 4 + r;
        vld[r] = (e < cnt);
        jn[r] = nbr_s[w][vld[r] ? e : (cnt - 1)];
      }
      float hjv[4][8];
      #pragma unroll
      for (int r = 0; r < 4; r++) {
        #pragma unroll
        for (int ct = 0; ct < 8; ct++)
          hjv[r][ct] = hj[((size_t)g * Nn + jn[r]) * 128 + ct * 16 + m16];
      }
      bf16x8 a0 = *(const bf16x8*)&A_lds[w][bf][m16 * 72 + quad * 8];
      bf16x8 a1 = *(const bf16x8*)&A_lds[w][bf][m16 * 72 + 32 + quad * 8];
      #pragma unroll
      for (int ct = 0; ct < 8; ct++) {
        f32x4 C = {0.f, 0.f, 0.f, 0.f};
        C = mfma16(a0, b0[ct].v, C);
        C = mfma16(a1, b1[ct].v, C);
        #pragma unroll
        for (int r = 0; r < 4; r++) {
          if (vld[r]) {
            float h = hiv[ct] + hjv[r][ct] + C[r];
            s1[ct] += h; s2[ct] += h * h;
            mxv[ct] = fmaxf(mxv[ct], h); mnv[ct] = fminf(mnv[ct], h);
          }
        }
      }
      #pragma unroll
      for (int x = 0; x < 8; x++) cr[x] = nr[x];
    }

    // cross-quad reduce: lanes {m16,+16,+32,+48} hold partials of the same col
    #pragma unroll
    for (int ct = 0; ct < 8; ct++) {
      #pragma unroll
      for (int off = 16; off <= 32; off <<= 1) {
        s1[ct] += __shfl_xor(s1[ct], off);
        s2[ct] += __shfl_xor(s2[ct], off);
        mxv[ct] = fmaxf(mxv[ct], __shfl_xor(mxv[ct], off));
        mnv[ct] = fminf(mnv[ct], __shfl_xor(mnv[ct], off));
      }
    }
    if (quad == 0) {
      float deg = (float)cnt, degc = fmaxf(deg, EPSF);
      float slog = logf(deg + 1.f) / AVGD;
      float inv  = 1.f / (slog + EPSF);
      int row = w;
      auto put = [&](int s, int col, float v) {
        uint32_t off = (uint32_t)(row * (KM * 2) + (s * 128 + col) * 2);
        off ^= (uint32_t)((row & 7) << 4);
        *(uint16_t*)((char*)m_s + off) = f2bf(v);
      };
      #pragma unroll
      for (int ct = 0; ct < 8; ct++) {
        int col = ct * 16 + m16;
        float mean = s1[ct] / degc;
        float var  = fmaxf(s2[ct] / degc - mean * mean, 0.f);
        float stdv = sqrtf(var + EPSF);
        float mx = mxv[ct], mn = mnv[ct];
        if (cnt == 0) { mx = 0.f; mn = 0.f; }
        put(0, col, mean);        put(1, col, mx);
        put(2, col, mn);          put(3, col, stdv);
        put(4, col, mean * slog); put(5, col, mx * slog);
        put(6, col, mn * slog);   put(7, col, stdv * slog);
        put(8, col, mean * inv);  put(9, col, mx * inv);
        put(10, col, mn * inv);   put(11, col, stdv * inv);
      }
    }
  }
  __syncthreads();   // m_s + hid_s ready

  // ---------------- post GEMM: K = 128 (raw input) + 1536 (LDS m) ----------------
  int col = w * 16 + m16;
  f32x4 acc0 = {0.f, 0.f, 0.f, 0.f}, acc1 = acc0;
  const uint16_t* bp = postTb + (size_t)col * KP + quad * 8;
  int ar = n0 + m16; if (ar > BN - 1) ar = BN - 1;   // rows 8..15: computed, not stored
  #pragma unroll
  for (int kt = 0; kt < 4; kt += 2) {
    bf16x8 a0 = load_a8(input, (size_t)ar * 128 + kt * 32 + quad * 8, isbf);
    bf16x8 a1 = load_a8(input, (size_t)ar * 128 + kt * 32 + 32 + quad * 8, isbf);
    acc0 = mfma16(a0, *(const bf16x8*)(bp + kt * 32), acc0);
    acc1 = mfma16(a1, *(const bf16x8*)(bp + kt * 32 + 32), acc1);
  }
  const uint16_t* bp2 = bp + 128;
  uint32_t mrb = (uint32_t)(m16 * (KM * 2));
  uint32_t msw = (uint32_t)((m16 & 7) << 4);
  #pragma unroll 4
  for (int kt = 0; kt < 48; kt += 2) {
    uint32_t o0 = (mrb + (kt * 32 + quad * 8) * 2) ^ msw;
    uint32_t o1 = (mrb + (kt * 32 + 32 + quad * 8) * 2) ^ msw;
    bf16x8 a0 = *(const bf16x8*)((const char*)m_s + o0);
    bf16x8 a1 = *(const bf16x8*)((const char*)m_s + o1);
    acc0 = mfma16(a0, *(const bf16x8*)(bp2 + kt * 32), acc0);
    acc1 = mfma16(a1, *(const bf16x8*)(bp2 + kt * 32 + 32), acc1);
  }
  float pb = loadf(post_b, col, isbf);
  #pragma unroll
  for (int r = 0; r < 4; r++)
    y_s[(quad * 4 + r) * SX + col] = f2bf(acc0[r] + acc1[r] + pb);
  __syncthreads();   // y_s ready

  // ---------------- mix + leaky ----------------
  f32x4 acc = {0.f, 0.f, 0.f, 0.f};
  const uint16_t* ya = &y_s[m16 * SX + quad * 8];
  const uint16_t* mb = mixTb + (size_t)col * 128 + quad * 8;
  #pragma unroll
  for (int kt = 0; kt < 4; kt++)
    acc = mfma16(*(const bf16x8*)(ya + kt * 32), *(const bf16x8*)(mb + kt * 32), acc);
  float mbias = loadf(mix_b, col, isbf);
  #pragma unroll
  for (int r = 0; r < 4; r++) {
    float v = acc[r] + mbias; v = v > 0.f ? v : LEAKF * v;
    x_s[(quad * 4 + r) * SX + col] = f2bf(v);
  }
  __syncthreads();   // x_s ready

  // ---------------- GRU ----------------
  f32x4 gi[3], gh[3];
  #pragma unroll
  for (int q = 0; q < 3; q++) { gi[q] = {0.f,0.f,0.f,0.f}; gh[q] = {0.f,0.f,0.f,0.f}; }
  const uint16_t* xa = &x_s[m16 * SX + quad * 8];
  const uint16_t* ha = &hid_s[m16 * SX + quad * 8];
  #pragma unroll
  for (int kt = 0; kt < 4; kt++) {
    bf16x8 ax = *(const bf16x8*)(xa + kt * 32);
    bf16x8 ah = *(const bf16x8*)(ha + kt * 32);
    #pragma unroll
    for (int q = 0; q < 3; q++) {
      bf16x8 bi_ = *(const bf16x8*)&Wihb[(size_t)(q * 128 + col) * 128 + kt * 32 + quad * 8];
      bf16x8 bh_ = *(const bf16x8*)&Whhb[(size_t)(q * 128 + col) * 128 + kt * 32 + quad * 8];
      gi[q] = mfma16(ax, bi_, gi[q]);
      gh[q] = mfma16(ah, bh_, gh[q]);
    }
  }
  #pragma unroll
  for (int r = 0; r < 4; r++) {
    int row = quad * 4 + r;
    if (row < 8) {   // block owns 8 nodes; rows 8..15 were padding
      float rg = 1.f / (1.f + expf(-(gi[0][r] + gh[0][r])));
      float zg = 1.f / (1.f + expf(-(gi[1][r] + gh[1][r])));
      float ng = tanhf(gi[2][r] + rg * gh[2][r]);
      float hv = bf2f(hid_s[row * SX + col]);
      float res = (1.f - zg) * ng + zg * hv;
      size_t oi = (size_t)(n0 + row) * 128 + col;
      if (isbf) ((uint16_t*)out)[oi] = f2bf(res);
      else      ((float*)out)[oi]    = res;
    }
  }
}

extern "C" void kernel_launch(void* const* d_in, const int* in_sizes, int n_in,
                              void* d_out, int out_size, void* d_ws, size_t ws_size,
                              hipStream_t stream) {
  const void* input  = d_in[0];
  const void* adj    = d_in[1];
  const void* af     = d_in[2];
  const void* hidden = d_in[3];
  const void* pre_W  = d_in[4];
  const void* pre_b  = d_in[5];
  const void* post_W = d_in[6];
  const void* post_b = d_in[7];
  const void* mix_W  = d_in[8];
  const void* mix_b  = d_in[9];
  const void* Wih    = d_in[10];
  const void* Whh    = d_in[11];

  float* ws = (float*)d_ws;
  float* hi = ws;                               // 262144 f
  float* hj = hi + 262144;                      // 262144 f
  uint16_t* postTb = (uint16_t*)(hj + 262144);  // 1664*128 = 212992
  uint16_t* mixTb  = postTb + 212992;           // 16384
  uint16_t* WeB    = mixTb + 16384;             // 64*128 = 8192
  uint16_t* Wihb   = WeB + 8192;                // 49152
  uint16_t* Whhb   = Wihb + 49152;              // 49152

  k_prep1<<<788, 256, 0, stream>>>(input, pre_W, pre_b, post_W, mix_W, Wih, Whh,
                                   postTb, mixTb, WeB, Wihb, Whhb, hi, hj);
  k23_fused<<<BN / 8, 512, 0, stream>>>(input, adj, af, hi, hj, WeB,
                                        postTb, post_b, mixTb, mix_b,
                                        Wihb, Whhb, hidden, d_out);
}